// Round 9
// baseline (252.962 us; speedup 1.0000x reference)
//
#include <hip/hip_runtime.h>

#define FDIM 128
#define NBMAX 512   // coarse buckets (dst>>8); supports n <= 131072
#define EPB 2048    // edges per block in hist/scatter phases
#define CPAD 16     // counter padding: one counter per 64-B line

typedef __attribute__((ext_vector_type(8))) short bf16x8;
typedef __attribute__((ext_vector_type(4))) float f32x4;

__device__ __forceinline__ unsigned short f2bf(float f) {
    unsigned int u = __float_as_uint(f);
    unsigned int r = u + 0x7fffu + ((u >> 16) & 1u);  // RNE
    return (unsigned short)(r >> 16);
}

// ---------------- D1: fused coarse histogram + W->bf16(hi) transpose ----------------
__global__ __launch_bounds__(256) void k_prep(const int* __restrict__ dst,
                                              int* __restrict__ bcnt,   // padded x16
                                              const float* __restrict__ W,
                                              unsigned short* __restrict__ whi,
                                              int e, int ebl) {
    __shared__ int h[NBMAX];
    if ((int)blockIdx.x < ebl) {
        for (int i = threadIdx.x; i < NBMAX; i += 256) h[i] = 0;
        __syncthreads();
        int base = blockIdx.x * EPB;
        int end = min(base + EPB, e);
        if (end - base == EPB && ((((size_t)(dst + base)) & 15) == 0)) {
            const int4* d4 = (const int4*)(dst + base);
            for (int i = threadIdx.x; i < EPB / 4; i += 256) {
                int4 v = d4[i];
                atomicAdd(&h[v.x >> 8], 1);
                atomicAdd(&h[v.y >> 8], 1);
                atomicAdd(&h[v.z >> 8], 1);
                atomicAdd(&h[v.w >> 8], 1);
            }
        } else {
            for (int i = base + threadIdx.x; i < end; i += 256) atomicAdd(&h[dst[i] >> 8], 1);
        }
        __syncthreads();
        for (int i = threadIdx.x; i < NBMAX; i += 256) {
            int c = h[i];
            if (c) atomicAdd(&bcnt[i * CPAD], c);
        }
    } else {
        int id = ((int)blockIdx.x - ebl) * 256 + threadIdx.x;  // 0..16383
        int k = id >> 7, nn = id & 127;
        whi[nn * FDIM + k] = f2bf(W[id]);  // W[k][nn] -> whi[nn][k]
    }
}

// ---------------- D2: single-block bucket scan -> bbase (removes per-block ladders) ----------------
__global__ __launch_bounds__(512) void k_bscan(const int* __restrict__ bcnt,  // padded x16
                                               int* __restrict__ bbase, int e) {
    __shared__ int sh[NBMAX];
    int v = bcnt[threadIdx.x * CPAD];
    sh[threadIdx.x] = v;
    __syncthreads();
    for (int off = 1; off < NBMAX; off <<= 1) {
        int t = (threadIdx.x >= off) ? sh[threadIdx.x - off] : 0;
        __syncthreads();
        sh[threadIdx.x] += t;
        __syncthreads();
    }
    bbase[threadIdx.x] = sh[threadIdx.x] - v;  // exclusive
    if (threadIdx.x == 0) bbase[NBMAX] = e;
}

// ---------------- D3: fused coarse scatter + MFMA GEMM ----------------
// blocks [0, ebl): scatterA -> coarse, bucket-contiguous (LDS counting sort);
//                  loads bbase[] (computed once by k_bscan) instead of per-block scan.
// blocks [ebl, ..): gemm    -> hs = bf16(x @ W), LDS-transposed coalesced epilogue.
__global__ __launch_bounds__(256) void k_main(
    const int* __restrict__ src, const int* __restrict__ dst,
    int* __restrict__ gcur,                       // padded x16
    const int* __restrict__ bbase,                // [NBMAX+1] from k_bscan
    unsigned int* __restrict__ coarse,
    const float* __restrict__ x, const unsigned short* __restrict__ whi,
    unsigned short* __restrict__ hs, int e, int n, int ebl) {
    union ShU {
        unsigned short Bs[FDIM * FDIM];           // 32 KB (gemm branch; also epilogue scratch)
        struct {
            int sval[EPB];                        // 8 KB sorted values
            unsigned short sbkt[EPB];             // 4 KB bucket id per slot
            int loff[NBMAX];                      // 2 KB local excl offsets
            int gbs[NBMAX];                       // 2 KB global chunk bases
        } sc;                                     // 16 KB (scatter branch)
    };
    __shared__ ShU S;
    __shared__ int cur[NBMAX];                    // 2 KB

    if ((int)blockIdx.x < ebl) {
        const int t = threadIdx.x;
        int* scr = S.sc.sval;  // scan scratch (free until sort)

        // ---- (a) local histogram ----
        cur[t] = 0;
        cur[t + 256] = 0;
        __syncthreads();
        int base = blockIdx.x * EPB;
        int end = min(base + EPB, e);
        int cnt = end - base;
        bool vec = (cnt == EPB) && ((((size_t)(dst + base)) & 15) == 0) &&
                   ((((size_t)(src + base)) & 15) == 0);
        if (vec) {
            const int4* d4 = (const int4*)(dst + base);
            for (int i = t; i < EPB / 4; i += 256) {
                int4 v = d4[i];
                atomicAdd(&cur[v.x >> 8], 1);
                atomicAdd(&cur[v.y >> 8], 1);
                atomicAdd(&cur[v.z >> 8], 1);
                atomicAdd(&cur[v.w >> 8], 1);
            }
        } else {
            for (int i = base + t; i < end; i += 256) atomicAdd(&cur[dst[i] >> 8], 1);
        }
        __syncthreads();

        // ---- (b) local excl scan of cur -> loff; global reservation + bbase -> gbs ----
        int c0 = cur[t], c1 = cur[t + 256];
        scr[t] = c0;
        scr[t + 256] = c1;
        __syncthreads();
        for (int off = 1; off < NBMAX; off <<= 1) {
            int a0 = (t >= off) ? scr[t - off] : 0;
            int a1 = (t + 256 >= off) ? scr[t + 256 - off] : 0;
            __syncthreads();
            scr[t] += a0;
            scr[t + 256] += a1;
            __syncthreads();
        }
        S.sc.loff[t] = scr[t] - c0;
        S.sc.loff[t + 256] = scr[t + 256] - c1;
        S.sc.gbs[t] = bbase[t] + (c0 ? atomicAdd(&gcur[t * CPAD], c0) : 0);
        S.sc.gbs[t + 256] = bbase[t + 256] + (c1 ? atomicAdd(&gcur[(t + 256) * CPAD], c1) : 0);
        cur[t] = 0;
        cur[t + 256] = 0;
        __syncthreads();

        // ---- (c) LDS counting sort ----
        if (vec) {
            const int4* d4 = (const int4*)(dst + base);
            const int4* s4 = (const int4*)(src + base);
            for (int i = t; i < EPB / 4; i += 256) {
                int4 dv = d4[i];
                int4 sv = s4[i];
                int b0 = dv.x >> 8, b1 = dv.y >> 8, b2 = dv.z >> 8, b3 = dv.w >> 8;
                int p0 = S.sc.loff[b0] + atomicAdd(&cur[b0], 1);
                int p1 = S.sc.loff[b1] + atomicAdd(&cur[b1], 1);
                int p2 = S.sc.loff[b2] + atomicAdd(&cur[b2], 1);
                int p3 = S.sc.loff[b3] + atomicAdd(&cur[b3], 1);
                S.sc.sval[p0] = (int)(((unsigned)sv.x << 8) | (unsigned)(dv.x & 255));
                S.sc.sbkt[p0] = (unsigned short)b0;
                S.sc.sval[p1] = (int)(((unsigned)sv.y << 8) | (unsigned)(dv.y & 255));
                S.sc.sbkt[p1] = (unsigned short)b1;
                S.sc.sval[p2] = (int)(((unsigned)sv.z << 8) | (unsigned)(dv.z & 255));
                S.sc.sbkt[p2] = (unsigned short)b2;
                S.sc.sval[p3] = (int)(((unsigned)sv.w << 8) | (unsigned)(dv.w & 255));
                S.sc.sbkt[p3] = (unsigned short)b3;
            }
        } else {
            for (int i = base + t; i < end; i += 256) {
                int d = dst[i];
                int b = d >> 8;
                int lp = atomicAdd(&cur[b], 1);
                int pos = S.sc.loff[b] + lp;
                S.sc.sval[pos] = (int)(((unsigned)src[i] << 8) | (unsigned)(d & 255));
                S.sc.sbkt[pos] = (unsigned short)b;
            }
        }
        __syncthreads();

        // ---- (d) contiguous flush ----
        for (int s = t; s < cnt; s += 256) {
            int b = S.sc.sbkt[s];
            coarse[S.sc.gbs[b] + (s - S.sc.loff[b])] = (unsigned)S.sc.sval[s];
        }
    } else {
        // ---- gemm ----
        {
            // stage whi with XOR swizzle on 16B granules: g -> g^(nn&15)
            const float4* g4 = (const float4*)whi;
            float4* l4 = (float4*)S.Bs;
            for (int i = threadIdx.x; i < 2048; i += 256) {
                int nn = i >> 4;
                int g = i & 15;
                l4[nn * 16 + (g ^ (nn & 15))] = g4[i];
            }
        }
        __syncthreads();

        const int lane = threadIdx.x & 63;
        const int wid = threadIdx.x >> 6;
        const int m = lane & 15;
        const int quad = lane >> 4;
        const int row0 = ((int)blockIdx.x - ebl) * 64 + wid * 16;

        int rowA = row0 + m;
        if (rowA >= n) rowA = n - 1;
        const float* xr = x + (size_t)rowA * FDIM;

        f32x4 acc[8];
        #pragma unroll
        for (int ct = 0; ct < 8; ++ct) acc[ct] = (f32x4){0.f, 0.f, 0.f, 0.f};

        #pragma unroll
        for (int kc = 0; kc < 4; ++kc) {
            const int kb = kc * 32 + quad * 8;
            float4 xa = *(const float4*)(xr + kb);
            float4 xb = *(const float4*)(xr + kb + 4);
            float v[8] = {xa.x, xa.y, xa.z, xa.w, xb.x, xb.y, xb.z, xb.w};
            bf16x8 ahi, alo;
            #pragma unroll
            for (int j = 0; j < 8; ++j) {
                unsigned short hh = f2bf(v[j]);
                ahi[j] = (short)hh;
                alo[j] = (short)f2bf(v[j] - __uint_as_float(((unsigned)hh) << 16));
            }
            const int g = kc * 4 + quad;
            #pragma unroll
            for (int ct = 0; ct < 8; ++ct) {
                int nidx = ct * 16 + m;
                const bf16x8 bhi = *(const bf16x8*)(S.Bs + (size_t)nidx * FDIM + (g ^ m) * 8);
                acc[ct] = __builtin_amdgcn_mfma_f32_16x16x32_bf16(ahi, bhi, acc[ct], 0, 0, 0);
                acc[ct] = __builtin_amdgcn_mfma_f32_16x16x32_bf16(alo, bhi, acc[ct], 0, 0, 0);
            }
        }

        // epilogue: transpose through LDS (Bs is dead now) -> full-line coalesced stores.
        __syncthreads();  // all waves done reading Bs
        {
            unsigned short* scratch = S.Bs + wid * (16 * FDIM);  // 4 KB per wave
            #pragma unroll
            for (int ct = 0; ct < 8; ++ct) {
                #pragma unroll
                for (int r = 0; r < 4; ++r) {
                    scratch[(quad * 4 + r) * FDIM + ct * 16 + m] = f2bf(acc[ct][r]);
                }
            }
            __syncthreads();
            #pragma unroll
            for (int it = 0; it < 4; ++it) {
                int rl = it * 4 + (lane >> 4);
                int row = row0 + rl;
                if (row < n) {
                    const uint4* pv = (const uint4*)(scratch + rl * FDIM + (lane & 15) * 8);
                    *((uint4*)(hs + (size_t)row * FDIM) + (lane & 15)) = *pv;
                }
            }
        }
    }
}

// ---------------- D4: fused per-bucket finalize (dinv, row_start, ebuf) ----------------
// Reads bbase[] from k_bscan.
__global__ __launch_bounds__(256) void k_bfin(const unsigned int* __restrict__ coarse,
                                              const int* __restrict__ bbase,
                                              float* __restrict__ dinv,
                                              int* __restrict__ row_start,
                                              int* __restrict__ ebuf, int n, int e) {
    __shared__ int ld[256];
    __shared__ int sc[256];
    __shared__ int cur[256];
    int b = blockIdx.x;
    int tt = threadIdx.x;
    int s = bbase[b], t = bbase[b + 1];
    if (b == 0 && tt == 0) row_start[n] = e;  // sentinel for gather

    ld[tt] = 0;
    __syncthreads();
    for (int i = s + tt; i < t; i += 256) atomicAdd(&ld[coarse[i] & 255u], 1);
    __syncthreads();
    int v = ld[tt];  // deg-1 of this node
    sc[tt] = v;
    __syncthreads();
    for (int off = 1; off < 256; off <<= 1) {
        int tv = (tt >= off) ? sc[tt - off] : 0;
        __syncthreads();
        sc[tt] += tv;
        __syncthreads();
    }
    int rs = s + sc[tt] - v;  // bucket base + exclusive scan
    cur[tt] = rs;
    int node = b * 256 + tt;
    if (node < n) {
        dinv[node] = rsqrtf((float)(v + 1));
        row_start[node] = rs;
    }
    __syncthreads();
    for (int i = s + tt; i < t; i += 256) {
        unsigned int p = coarse[i];
        int pos = atomicAdd(&cur[p & 255u], 1);
        ebuf[pos] = (int)(p >> 8);
    }
}

// ---------------- D5: gather: out[i] = dinv[i]*(dinv[i]*h[i] + sum dinv[s]*h[s]) + b ----------------
// persistent grid-stride waves (node per wave), 8-edge unrolled + software-pipelined
// ebuf index loads. Bias hoisted out of the node loop.  (Round-4 verified, verbatim.)
__global__ __launch_bounds__(256, 8) void k_gather(
    const unsigned short* __restrict__ hs, const int* __restrict__ ebuf,
    const int* __restrict__ row_start, const float* __restrict__ dinv,
    const float* __restrict__ bias, float* __restrict__ out, int n) {
    const int lane = threadIdx.x & 63;
    const int gw = (int)blockIdx.x * 4 + (threadIdx.x >> 6);
    const int nw = (int)gridDim.x * 4;

    const unsigned int* __restrict__ hl = (const unsigned int*)hs + lane;
    const float2 bb = ((const float2*)bias)[lane];

    for (int i = gw; i < n; i += nw) {
        int beg = row_start[i];
        int end = row_start[i + 1];
        float di = dinv[i];

        unsigned int u = hl[(unsigned)i << 6];
        float ax = di * __uint_as_float(u << 16);
        float ay = di * __uint_as_float(u & 0xffff0000u);
        float bx = 0.f, by = 0.f;

        int j = beg;
        int stop8 = j + ((end - j) & ~7);
        if (j < stop8) {
            int s0 = ebuf[j + 0], s1 = ebuf[j + 1], s2 = ebuf[j + 2], s3 = ebuf[j + 3];
            int s4 = ebuf[j + 4], s5 = ebuf[j + 5], s6 = ebuf[j + 6], s7 = ebuf[j + 7];
            j += 8;
            while (j < stop8) {
                unsigned int u0 = hl[(unsigned)s0 << 6], u1 = hl[(unsigned)s1 << 6];
                unsigned int u2 = hl[(unsigned)s2 << 6], u3 = hl[(unsigned)s3 << 6];
                unsigned int u4 = hl[(unsigned)s4 << 6], u5 = hl[(unsigned)s5 << 6];
                unsigned int u6 = hl[(unsigned)s6 << 6], u7 = hl[(unsigned)s7 << 6];
                float d0 = dinv[s0], d1 = dinv[s1], d2 = dinv[s2], d3 = dinv[s3];
                float d4 = dinv[s4], d5 = dinv[s5], d6 = dinv[s6], d7 = dinv[s7];
                int t0 = ebuf[j + 0], t1 = ebuf[j + 1], t2 = ebuf[j + 2], t3 = ebuf[j + 3];
                int t4 = ebuf[j + 4], t5 = ebuf[j + 5], t6 = ebuf[j + 6], t7 = ebuf[j + 7];
                ax = fmaf(d0, __uint_as_float(u0 << 16), ax);
                ay = fmaf(d0, __uint_as_float(u0 & 0xffff0000u), ay);
                bx = fmaf(d1, __uint_as_float(u1 << 16), bx);
                by = fmaf(d1, __uint_as_float(u1 & 0xffff0000u), by);
                ax = fmaf(d2, __uint_as_float(u2 << 16), ax);
                ay = fmaf(d2, __uint_as_float(u2 & 0xffff0000u), ay);
                bx = fmaf(d3, __uint_as_float(u3 << 16), bx);
                by = fmaf(d3, __uint_as_float(u3 & 0xffff0000u), by);
                ax = fmaf(d4, __uint_as_float(u4 << 16), ax);
                ay = fmaf(d4, __uint_as_float(u4 & 0xffff0000u), ay);
                bx = fmaf(d5, __uint_as_float(u5 << 16), bx);
                by = fmaf(d5, __uint_as_float(u5 & 0xffff0000u), by);
                ax = fmaf(d6, __uint_as_float(u6 << 16), ax);
                ay = fmaf(d6, __uint_as_float(u6 & 0xffff0000u), ay);
                bx = fmaf(d7, __uint_as_float(u7 << 16), bx);
                by = fmaf(d7, __uint_as_float(u7 & 0xffff0000u), by);
                s0 = t0; s1 = t1; s2 = t2; s3 = t3;
                s4 = t4; s5 = t5; s6 = t6; s7 = t7;
                j += 8;
            }
            {
                unsigned int u0 = hl[(unsigned)s0 << 6], u1 = hl[(unsigned)s1 << 6];
                unsigned int u2 = hl[(unsigned)s2 << 6], u3 = hl[(unsigned)s3 << 6];
                unsigned int u4 = hl[(unsigned)s4 << 6], u5 = hl[(unsigned)s5 << 6];
                unsigned int u6 = hl[(unsigned)s6 << 6], u7 = hl[(unsigned)s7 << 6];
                float d0 = dinv[s0], d1 = dinv[s1], d2 = dinv[s2], d3 = dinv[s3];
                float d4 = dinv[s4], d5 = dinv[s5], d6 = dinv[s6], d7 = dinv[s7];
                ax = fmaf(d0, __uint_as_float(u0 << 16), ax);
                ay = fmaf(d0, __uint_as_float(u0 & 0xffff0000u), ay);
                bx = fmaf(d1, __uint_as_float(u1 << 16), bx);
                by = fmaf(d1, __uint_as_float(u1 & 0xffff0000u), by);
                ax = fmaf(d2, __uint_as_float(u2 << 16), ax);
                ay = fmaf(d2, __uint_as_float(u2 & 0xffff0000u), ay);
                bx = fmaf(d3, __uint_as_float(u3 << 16), bx);
                by = fmaf(d3, __uint_as_float(u3 & 0xffff0000u), by);
                ax = fmaf(d4, __uint_as_float(u4 << 16), ax);
                ay = fmaf(d4, __uint_as_float(u4 & 0xffff0000u), ay);
                bx = fmaf(d5, __uint_as_float(u5 << 16), bx);
                by = fmaf(d5, __uint_as_float(u5 & 0xffff0000u), by);
                ax = fmaf(d6, __uint_as_float(u6 << 16), ax);
                ay = fmaf(d6, __uint_as_float(u6 & 0xffff0000u), ay);
                bx = fmaf(d7, __uint_as_float(u7 << 16), bx);
                by = fmaf(d7, __uint_as_float(u7 & 0xffff0000u), by);
            }
        }
        for (; j + 3 < end; j += 4) {
            int s0 = ebuf[j], s1 = ebuf[j + 1], s2 = ebuf[j + 2], s3 = ebuf[j + 3];
            float d0 = dinv[s0], d1 = dinv[s1], d2 = dinv[s2], d3 = dinv[s3];
            unsigned int u0 = hl[(unsigned)s0 << 6];
            unsigned int u1 = hl[(unsigned)s1 << 6];
            unsigned int u2 = hl[(unsigned)s2 << 6];
            unsigned int u3 = hl[(unsigned)s3 << 6];
            ax = fmaf(d0, __uint_as_float(u0 << 16), ax);
            ay = fmaf(d0, __uint_as_float(u0 & 0xffff0000u), ay);
            bx = fmaf(d1, __uint_as_float(u1 << 16), bx);
            by = fmaf(d1, __uint_as_float(u1 & 0xffff0000u), by);
            ax = fmaf(d2, __uint_as_float(u2 << 16), ax);
            ay = fmaf(d2, __uint_as_float(u2 & 0xffff0000u), ay);
            bx = fmaf(d3, __uint_as_float(u3 << 16), bx);
            by = fmaf(d3, __uint_as_float(u3 & 0xffff0000u), by);
        }
        for (; j < end; ++j) {
            int s0 = ebuf[j];
            float d0 = dinv[s0];
            unsigned int u0 = hl[(unsigned)s0 << 6];
            ax = fmaf(d0, __uint_as_float(u0 << 16), ax);
            ay = fmaf(d0, __uint_as_float(u0 & 0xffff0000u), ay);
        }
        ax += bx;
        ay += by;

        float2 r = make_float2(fmaf(ax, di, bb.x), fmaf(ay, di, bb.y));
        ((float2*)(out + (size_t)i * FDIM))[lane] = r;
    }
}

extern "C" void kernel_launch(void* const* d_in, const int* in_sizes, int n_in,
                              void* d_out, int out_size, void* d_ws, size_t ws_size,
                              hipStream_t stream) {
    const float* x  = (const float*)d_in[0];
    const int*   ei = (const int*)d_in[1];     // [2, E] int32
    const float* W  = (const float*)d_in[2];
    const float* b  = (const float*)d_in[3];

    const int n = in_sizes[0] / FDIM;
    const int e = in_sizes[1] / 2;
    const int* src = ei;
    const int* dst = ei + e;
    float* out = (float*)d_out;

    const int nb = (n + 255) >> 8;              // node buckets
    const int ebl = (e + EPB - 1) / EPB;        // edge blocks
    const int gemmbl = (n + 63) / 64;

    char* ws = (char*)d_ws;
    size_t off = 0;
    auto alloc = [&](size_t bytes) {
        char* p = ws + off;
        off += (bytes + 511) & ~(size_t)511;
        return p;
    };
    float*          dinv      = (float*)alloc((size_t)n * 4);
    int*            row_start = (int*)alloc((size_t)(n + 1) * 4);
    int*            bcnt      = (int*)alloc((size_t)NBMAX * CPAD * 4);  // padded; adjacent:
    int*            gcur      = (int*)alloc((size_t)NBMAX * CPAD * 4);  // one memset covers both
    int*            bbase     = (int*)alloc((size_t)(NBMAX + 1) * 4);
    unsigned short* whi       = (unsigned short*)alloc((size_t)FDIM * FDIM * 2);
    unsigned int*   coarse    = (unsigned int*)alloc((size_t)e * 4);
    int*            ebuf      = (int*)alloc((size_t)e * 4);
    unsigned short* hs        = (unsigned short*)alloc((size_t)n * FDIM * 2);

    hipMemsetAsync(bcnt, 0, (size_t)NBMAX * CPAD * 4 * 2, stream);  // bcnt + gcur

    k_prep<<<ebl + 64, 256, 0, stream>>>(dst, bcnt, W, whi, e, ebl);
    k_bscan<<<1, 512, 0, stream>>>(bcnt, bbase, e);
    k_main<<<ebl + gemmbl, 256, 0, stream>>>(src, dst, gcur, bbase, coarse, x, whi, hs, e, n, ebl);
    k_bfin<<<nb, 256, 0, stream>>>(coarse, bbase, dinv, row_start, ebuf, n, e);
    {
        int blocks = (n + 3) / 4;
        if (blocks > 2048) blocks = 2048;
        k_gather<<<blocks, 256, 0, stream>>>(hs, ebuf, row_start, dinv, b, out, n);
    }
}

// Round 10
// 217.149 us; speedup vs baseline: 1.1649x; 1.1649x over previous
//
#include <hip/hip_runtime.h>

#define FDIM 128
#define NBMAX 512   // coarse buckets (dst>>8); supports n <= 131072
#define EPB 4096    // edges per block in hist/scatter phases
#define CPAD 16     // counter padding: one counter per 64-B line

typedef __attribute__((ext_vector_type(8))) short bf16x8;
typedef __attribute__((ext_vector_type(4))) float f32x4;

__device__ __forceinline__ unsigned short f2bf(float f) {
    unsigned int u = __float_as_uint(f);
    unsigned int r = u + 0x7fffu + ((u >> 16) & 1u);  // RNE
    return (unsigned short)(r >> 16);
}

// ---------------- D1: fused coarse histogram + W->bf16(hi) transpose (512 thr) ----------------
__global__ __launch_bounds__(512) void k_prep(const int* __restrict__ dst,
                                              int* __restrict__ bcnt,   // padded x16
                                              const float* __restrict__ W,
                                              unsigned short* __restrict__ whi,
                                              int e, int ebl) {
    __shared__ int h[NBMAX];
    if ((int)blockIdx.x < ebl) {
        h[threadIdx.x] = 0;  // blockDim == NBMAX
        __syncthreads();
        int base = blockIdx.x * EPB;
        int end = min(base + EPB, e);
        if (end - base == EPB && ((((size_t)(dst + base)) & 15) == 0)) {
            const int4* d4 = (const int4*)(dst + base);
            for (int i = threadIdx.x; i < EPB / 4; i += 512) {
                int4 v = d4[i];
                atomicAdd(&h[v.x >> 8], 1);
                atomicAdd(&h[v.y >> 8], 1);
                atomicAdd(&h[v.z >> 8], 1);
                atomicAdd(&h[v.w >> 8], 1);
            }
        } else {
            for (int i = base + threadIdx.x; i < end; i += 512) atomicAdd(&h[dst[i] >> 8], 1);
        }
        __syncthreads();
        int c = h[threadIdx.x];
        if (c) atomicAdd(&bcnt[threadIdx.x * CPAD], c);
    } else {
        int id = ((int)blockIdx.x - ebl) * 512 + threadIdx.x;  // 0..16383 over 32 blocks
        int k = id >> 7, nn = id & 127;
        whi[nn * FDIM + k] = f2bf(W[id]);  // W[k][nn] -> whi[nn][k]
    }
}

// ---------------- D3: fused coarse scatter + MFMA GEMM (512 thr) ----------------
// blocks [0, ebl): scatterA -> coarse, bucket-contiguous (LDS counting sort);
//                  block 0 also publishes bbase[] (exclusive bucket bases) for k_bfin.
// blocks [ebl, ..): gemm    -> hs = bf16(x @ W), 8 waves = 128 rows/block,
//                   LDS-transposed coalesced epilogue.
__global__ __launch_bounds__(512) void k_main(
    const int* __restrict__ src, const int* __restrict__ dst,
    const int* __restrict__ bcnt,                 // padded x16
    int* __restrict__ gcur,                       // padded x16
    int* __restrict__ bbase,                      // [NBMAX+1] published by block 0
    unsigned int* __restrict__ coarse,
    const float* __restrict__ x, const unsigned short* __restrict__ whi,
    unsigned short* __restrict__ hs, int e, int n, int ebl) {
    union ShU {
        unsigned short Bs[FDIM * FDIM];           // 32 KB (gemm branch; also epilogue scratch)
        struct {
            int sval[EPB];                        // 16 KB sorted values
            unsigned short sbkt[EPB];             // 8 KB bucket id per slot
            int loff[NBMAX];                      // 2 KB local excl offsets
            int gbs[NBMAX];                       // 2 KB global chunk bases
        } sc;                                     // 28 KB (scatter branch)
    };
    __shared__ ShU S;
    __shared__ int cur[NBMAX];                    // 2 KB
    __shared__ int bb[NBMAX];                     // 2 KB

    if ((int)blockIdx.x < ebl) {
        const int t = threadIdx.x;                // 0..511 == bucket id
        int* scr = S.sc.sval;  // scan scratch (free until sort)

        // ---- (a) excl scan of global bcnt -> bb (1 elem/thread) ----
        int v0 = bcnt[t * CPAD];
        scr[t] = v0;
        __syncthreads();
        for (int off = 1; off < NBMAX; off <<= 1) {
            int a0 = (t >= off) ? scr[t - off] : 0;
            __syncthreads();
            scr[t] += a0;
            __syncthreads();
        }
        int ex0 = scr[t] - v0;
        bb[t] = ex0;
        if (blockIdx.x == 0) {  // publish for k_bfin
            bbase[t] = ex0;
            if (t == 0) bbase[NBMAX] = e;
        }

        // ---- (b) local histogram ----
        cur[t] = 0;
        __syncthreads();
        int base = blockIdx.x * EPB;
        int end = min(base + EPB, e);
        int cnt = end - base;
        bool vec = (cnt == EPB) && ((((size_t)(dst + base)) & 15) == 0) &&
                   ((((size_t)(src + base)) & 15) == 0);
        if (vec) {
            const int4* d4 = (const int4*)(dst + base);
            for (int i = t; i < EPB / 4; i += 512) {
                int4 v = d4[i];
                atomicAdd(&cur[v.x >> 8], 1);
                atomicAdd(&cur[v.y >> 8], 1);
                atomicAdd(&cur[v.z >> 8], 1);
                atomicAdd(&cur[v.w >> 8], 1);
            }
        } else {
            for (int i = base + t; i < end; i += 512) atomicAdd(&cur[dst[i] >> 8], 1);
        }
        __syncthreads();

        // local excl scan of cur -> loff, and global reservation -> gbs
        int c0 = cur[t];
        scr[t] = c0;
        __syncthreads();
        for (int off = 1; off < NBMAX; off <<= 1) {
            int a0 = (t >= off) ? scr[t - off] : 0;
            __syncthreads();
            scr[t] += a0;
            __syncthreads();
        }
        S.sc.loff[t] = scr[t] - c0;
        S.sc.gbs[t] = bb[t] + (c0 ? atomicAdd(&gcur[t * CPAD], c0) : 0);
        cur[t] = 0;
        __syncthreads();

        // ---- (c) LDS counting sort ----
        if (vec) {
            const int4* d4 = (const int4*)(dst + base);
            const int4* s4 = (const int4*)(src + base);
            for (int i = t; i < EPB / 4; i += 512) {
                int4 dv = d4[i];
                int4 sv = s4[i];
                int b0 = dv.x >> 8, b1 = dv.y >> 8, b2 = dv.z >> 8, b3 = dv.w >> 8;
                int p0 = S.sc.loff[b0] + atomicAdd(&cur[b0], 1);
                int p1 = S.sc.loff[b1] + atomicAdd(&cur[b1], 1);
                int p2 = S.sc.loff[b2] + atomicAdd(&cur[b2], 1);
                int p3 = S.sc.loff[b3] + atomicAdd(&cur[b3], 1);
                S.sc.sval[p0] = (int)(((unsigned)sv.x << 8) | (unsigned)(dv.x & 255));
                S.sc.sbkt[p0] = (unsigned short)b0;
                S.sc.sval[p1] = (int)(((unsigned)sv.y << 8) | (unsigned)(dv.y & 255));
                S.sc.sbkt[p1] = (unsigned short)b1;
                S.sc.sval[p2] = (int)(((unsigned)sv.z << 8) | (unsigned)(dv.z & 255));
                S.sc.sbkt[p2] = (unsigned short)b2;
                S.sc.sval[p3] = (int)(((unsigned)sv.w << 8) | (unsigned)(dv.w & 255));
                S.sc.sbkt[p3] = (unsigned short)b3;
            }
        } else {
            for (int i = base + t; i < end; i += 512) {
                int d = dst[i];
                int b = d >> 8;
                int lp = atomicAdd(&cur[b], 1);
                int pos = S.sc.loff[b] + lp;
                S.sc.sval[pos] = (int)(((unsigned)src[i] << 8) | (unsigned)(d & 255));
                S.sc.sbkt[pos] = (unsigned short)b;
            }
        }
        __syncthreads();

        // ---- (d) contiguous flush ----
        for (int s = t; s < cnt; s += 512) {
            int b = S.sc.sbkt[s];
            coarse[S.sc.gbs[b] + (s - S.sc.loff[b])] = (unsigned)S.sc.sval[s];
        }
    } else {
        // ---- gemm: 8 waves -> 128 rows/block ----
        {
            // stage whi with XOR swizzle on 16B granules: g -> g^(nn&15)
            const float4* g4 = (const float4*)whi;
            float4* l4 = (float4*)S.Bs;
            for (int i = threadIdx.x; i < 2048; i += 512) {
                int nn = i >> 4;
                int g = i & 15;
                l4[nn * 16 + (g ^ (nn & 15))] = g4[i];
            }
        }
        __syncthreads();

        const int lane = threadIdx.x & 63;
        const int wid = threadIdx.x >> 6;        // 0..7
        const int m = lane & 15;
        const int quad = lane >> 4;
        const int row0 = ((int)blockIdx.x - ebl) * 128 + wid * 16;

        int rowA = row0 + m;
        if (rowA >= n) rowA = n - 1;
        const float* xr = x + (size_t)rowA * FDIM;

        f32x4 acc[8];
        #pragma unroll
        for (int ct = 0; ct < 8; ++ct) acc[ct] = (f32x4){0.f, 0.f, 0.f, 0.f};

        #pragma unroll
        for (int kc = 0; kc < 4; ++kc) {
            const int kb = kc * 32 + quad * 8;
            float4 xa = *(const float4*)(xr + kb);
            float4 xb = *(const float4*)(xr + kb + 4);
            float v[8] = {xa.x, xa.y, xa.z, xa.w, xb.x, xb.y, xb.z, xb.w};
            bf16x8 ahi, alo;
            #pragma unroll
            for (int j = 0; j < 8; ++j) {
                unsigned short hh = f2bf(v[j]);
                ahi[j] = (short)hh;
                alo[j] = (short)f2bf(v[j] - __uint_as_float(((unsigned)hh) << 16));
            }
            const int g = kc * 4 + quad;
            #pragma unroll
            for (int ct = 0; ct < 8; ++ct) {
                int nidx = ct * 16 + m;
                const bf16x8 bhi = *(const bf16x8*)(S.Bs + (size_t)nidx * FDIM + (g ^ m) * 8);
                acc[ct] = __builtin_amdgcn_mfma_f32_16x16x32_bf16(ahi, bhi, acc[ct], 0, 0, 0);
                acc[ct] = __builtin_amdgcn_mfma_f32_16x16x32_bf16(alo, bhi, acc[ct], 0, 0, 0);
            }
        }

        // epilogue: transpose through LDS (Bs dead) -> full-line coalesced stores.
        __syncthreads();  // all 8 waves done reading Bs
        {
            unsigned short* scratch = S.Bs + wid * (16 * FDIM);  // 4 KB per wave, 8x4=32KB=Bs
            #pragma unroll
            for (int ct = 0; ct < 8; ++ct) {
                #pragma unroll
                for (int r = 0; r < 4; ++r) {
                    scratch[(quad * 4 + r) * FDIM + ct * 16 + m] = f2bf(acc[ct][r]);
                }
            }
            __syncthreads();
            #pragma unroll
            for (int it = 0; it < 4; ++it) {
                int rl = it * 4 + (lane >> 4);
                int row = row0 + rl;
                if (row < n) {
                    const uint4* pv = (const uint4*)(scratch + rl * FDIM + (lane & 15) * 8);
                    *((uint4*)(hs + (size_t)row * FDIM) + (lane & 15)) = *pv;
                }
            }
        }
    }
}

// ---------------- D4: fused per-bucket finalize (512 thr; reads published bbase) ----------------
__global__ __launch_bounds__(512) void k_bfin(const unsigned int* __restrict__ coarse,
                                              const int* __restrict__ bbase,
                                              float* __restrict__ dinv,
                                              int* __restrict__ row_start,
                                              int* __restrict__ ebuf, int n, int e) {
    __shared__ int ld[256];
    __shared__ int sc[256];
    __shared__ int cur[256];
    int b = blockIdx.x;
    int tt = threadIdx.x;
    int s = bbase[b], t = bbase[b + 1];
    if (b == 0 && tt == 0) row_start[n] = e;  // sentinel for gather

    if (tt < 256) ld[tt] = 0;
    __syncthreads();
    for (int i = s + tt; i < t; i += 512) atomicAdd(&ld[coarse[i] & 255u], 1);
    __syncthreads();
    int v = (tt < 256) ? ld[tt] : 0;  // deg-1 of this node
    if (tt < 256) sc[tt] = v;
    __syncthreads();
    for (int off = 1; off < 256; off <<= 1) {
        int tv = (tt >= off && tt < 256) ? sc[tt - off] : 0;
        __syncthreads();
        if (tt < 256) sc[tt] += tv;
        __syncthreads();
    }
    if (tt < 256) {
        int rs = s + sc[tt] - v;  // bucket base + exclusive scan
        cur[tt] = rs;
        int node = b * 256 + tt;
        if (node < n) {
            dinv[node] = rsqrtf((float)(v + 1));
            row_start[node] = rs;
        }
    }
    __syncthreads();
    for (int i = s + tt; i < t; i += 512) {
        unsigned int p = coarse[i];
        int pos = atomicAdd(&cur[p & 255u], 1);
        ebuf[pos] = (int)(p >> 8);
    }
}

// ---------------- D5: gather: out[i] = dinv[i]*(dinv[i]*h[i] + sum dinv[s]*h[s]) + b ----------------
// persistent grid-stride waves (node per wave), 8-edge unrolled + software-pipelined
// ebuf index loads. Bias hoisted out of the node loop.  (Round-4 verified, verbatim.)
__global__ __launch_bounds__(256, 8) void k_gather(
    const unsigned short* __restrict__ hs, const int* __restrict__ ebuf,
    const int* __restrict__ row_start, const float* __restrict__ dinv,
    const float* __restrict__ bias, float* __restrict__ out, int n) {
    const int lane = threadIdx.x & 63;
    const int gw = (int)blockIdx.x * 4 + (threadIdx.x >> 6);
    const int nw = (int)gridDim.x * 4;

    const unsigned int* __restrict__ hl = (const unsigned int*)hs + lane;
    const float2 bb = ((const float2*)bias)[lane];

    for (int i = gw; i < n; i += nw) {
        int beg = row_start[i];
        int end = row_start[i + 1];
        float di = dinv[i];

        unsigned int u = hl[(unsigned)i << 6];
        float ax = di * __uint_as_float(u << 16);
        float ay = di * __uint_as_float(u & 0xffff0000u);
        float bx = 0.f, by = 0.f;

        int j = beg;
        int stop8 = j + ((end - j) & ~7);
        if (j < stop8) {
            int s0 = ebuf[j + 0], s1 = ebuf[j + 1], s2 = ebuf[j + 2], s3 = ebuf[j + 3];
            int s4 = ebuf[j + 4], s5 = ebuf[j + 5], s6 = ebuf[j + 6], s7 = ebuf[j + 7];
            j += 8;
            while (j < stop8) {
                unsigned int u0 = hl[(unsigned)s0 << 6], u1 = hl[(unsigned)s1 << 6];
                unsigned int u2 = hl[(unsigned)s2 << 6], u3 = hl[(unsigned)s3 << 6];
                unsigned int u4 = hl[(unsigned)s4 << 6], u5 = hl[(unsigned)s5 << 6];
                unsigned int u6 = hl[(unsigned)s6 << 6], u7 = hl[(unsigned)s7 << 6];
                float d0 = dinv[s0], d1 = dinv[s1], d2 = dinv[s2], d3 = dinv[s3];
                float d4 = dinv[s4], d5 = dinv[s5], d6 = dinv[s6], d7 = dinv[s7];
                int t0 = ebuf[j + 0], t1 = ebuf[j + 1], t2 = ebuf[j + 2], t3 = ebuf[j + 3];
                int t4 = ebuf[j + 4], t5 = ebuf[j + 5], t6 = ebuf[j + 6], t7 = ebuf[j + 7];
                ax = fmaf(d0, __uint_as_float(u0 << 16), ax);
                ay = fmaf(d0, __uint_as_float(u0 & 0xffff0000u), ay);
                bx = fmaf(d1, __uint_as_float(u1 << 16), bx);
                by = fmaf(d1, __uint_as_float(u1 & 0xffff0000u), by);
                ax = fmaf(d2, __uint_as_float(u2 << 16), ax);
                ay = fmaf(d2, __uint_as_float(u2 & 0xffff0000u), ay);
                bx = fmaf(d3, __uint_as_float(u3 << 16), bx);
                by = fmaf(d3, __uint_as_float(u3 & 0xffff0000u), by);
                ax = fmaf(d4, __uint_as_float(u4 << 16), ax);
                ay = fmaf(d4, __uint_as_float(u4 & 0xffff0000u), ay);
                bx = fmaf(d5, __uint_as_float(u5 << 16), bx);
                by = fmaf(d5, __uint_as_float(u5 & 0xffff0000u), by);
                ax = fmaf(d6, __uint_as_float(u6 << 16), ax);
                ay = fmaf(d6, __uint_as_float(u6 & 0xffff0000u), ay);
                bx = fmaf(d7, __uint_as_float(u7 << 16), bx);
                by = fmaf(d7, __uint_as_float(u7 & 0xffff0000u), by);
                s0 = t0; s1 = t1; s2 = t2; s3 = t3;
                s4 = t4; s5 = t5; s6 = t6; s7 = t7;
                j += 8;
            }
            {
                unsigned int u0 = hl[(unsigned)s0 << 6], u1 = hl[(unsigned)s1 << 6];
                unsigned int u2 = hl[(unsigned)s2 << 6], u3 = hl[(unsigned)s3 << 6];
                unsigned int u4 = hl[(unsigned)s4 << 6], u5 = hl[(unsigned)s5 << 6];
                unsigned int u6 = hl[(unsigned)s6 << 6], u7 = hl[(unsigned)s7 << 6];
                float d0 = dinv[s0], d1 = dinv[s1], d2 = dinv[s2], d3 = dinv[s3];
                float d4 = dinv[s4], d5 = dinv[s5], d6 = dinv[s6], d7 = dinv[s7];
                ax = fmaf(d0, __uint_as_float(u0 << 16), ax);
                ay = fmaf(d0, __uint_as_float(u0 & 0xffff0000u), ay);
                bx = fmaf(d1, __uint_as_float(u1 << 16), bx);
                by = fmaf(d1, __uint_as_float(u1 & 0xffff0000u), by);
                ax = fmaf(d2, __uint_as_float(u2 << 16), ax);
                ay = fmaf(d2, __uint_as_float(u2 & 0xffff0000u), ay);
                bx = fmaf(d3, __uint_as_float(u3 << 16), bx);
                by = fmaf(d3, __uint_as_float(u3 & 0xffff0000u), by);
                ax = fmaf(d4, __uint_as_float(u4 << 16), ax);
                ay = fmaf(d4, __uint_as_float(u4 & 0xffff0000u), ay);
                bx = fmaf(d5, __uint_as_float(u5 << 16), bx);
                by = fmaf(d5, __uint_as_float(u5 & 0xffff0000u), by);
                ax = fmaf(d6, __uint_as_float(u6 << 16), ax);
                ay = fmaf(d6, __uint_as_float(u6 & 0xffff0000u), ay);
                bx = fmaf(d7, __uint_as_float(u7 << 16), bx);
                by = fmaf(d7, __uint_as_float(u7 & 0xffff0000u), by);
            }
        }
        for (; j + 3 < end; j += 4) {
            int s0 = ebuf[j], s1 = ebuf[j + 1], s2 = ebuf[j + 2], s3 = ebuf[j + 3];
            float d0 = dinv[s0], d1 = dinv[s1], d2 = dinv[s2], d3 = dinv[s3];
            unsigned int u0 = hl[(unsigned)s0 << 6];
            unsigned int u1 = hl[(unsigned)s1 << 6];
            unsigned int u2 = hl[(unsigned)s2 << 6];
            unsigned int u3 = hl[(unsigned)s3 << 6];
            ax = fmaf(d0, __uint_as_float(u0 << 16), ax);
            ay = fmaf(d0, __uint_as_float(u0 & 0xffff0000u), ay);
            bx = fmaf(d1, __uint_as_float(u1 << 16), bx);
            by = fmaf(d1, __uint_as_float(u1 & 0xffff0000u), by);
            ax = fmaf(d2, __uint_as_float(u2 << 16), ax);
            ay = fmaf(d2, __uint_as_float(u2 & 0xffff0000u), ay);
            bx = fmaf(d3, __uint_as_float(u3 << 16), bx);
            by = fmaf(d3, __uint_as_float(u3 & 0xffff0000u), by);
        }
        for (; j < end; ++j) {
            int s0 = ebuf[j];
            float d0 = dinv[s0];
            unsigned int u0 = hl[(unsigned)s0 << 6];
            ax = fmaf(d0, __uint_as_float(u0 << 16), ax);
            ay = fmaf(d0, __uint_as_float(u0 & 0xffff0000u), ay);
        }
        ax += bx;
        ay += by;

        float2 r = make_float2(fmaf(ax, di, bb.x), fmaf(ay, di, bb.y));
        ((float2*)(out + (size_t)i * FDIM))[lane] = r;
    }
}

extern "C" void kernel_launch(void* const* d_in, const int* in_sizes, int n_in,
                              void* d_out, int out_size, void* d_ws, size_t ws_size,
                              hipStream_t stream) {
    const float* x  = (const float*)d_in[0];
    const int*   ei = (const int*)d_in[1];     // [2, E] int32
    const float* W  = (const float*)d_in[2];
    const float* b  = (const float*)d_in[3];

    const int n = in_sizes[0] / FDIM;
    const int e = in_sizes[1] / 2;
    const int* src = ei;
    const int* dst = ei + e;
    float* out = (float*)d_out;

    const int nb = (n + 255) >> 8;              // node buckets
    const int ebl = (e + EPB - 1) / EPB;        // edge blocks
    const int gemmbl = (n + 127) / 128;         // 128 rows/block (8 waves)

    char* ws = (char*)d_ws;
    size_t off = 0;
    auto alloc = [&](size_t bytes) {
        char* p = ws + off;
        off += (bytes + 511) & ~(size_t)511;
        return p;
    };
    float*          dinv      = (float*)alloc((size_t)n * 4);
    int*            row_start = (int*)alloc((size_t)(n + 1) * 4);
    int*            bcnt      = (int*)alloc((size_t)NBMAX * CPAD * 4);  // padded; adjacent:
    int*            gcur      = (int*)alloc((size_t)NBMAX * CPAD * 4);  // one memset covers both
    int*            bbase     = (int*)alloc((size_t)(NBMAX + 1) * 4);
    unsigned short* whi       = (unsigned short*)alloc((size_t)FDIM * FDIM * 2);
    unsigned int*   coarse    = (unsigned int*)alloc((size_t)e * 4);
    int*            ebuf      = (int*)alloc((size_t)e * 4);
    unsigned short* hs        = (unsigned short*)alloc((size_t)n * FDIM * 2);

    hipMemsetAsync(bcnt, 0, (size_t)NBMAX * CPAD * 4 * 2, stream);  // bcnt + gcur

    k_prep<<<ebl + 32, 512, 0, stream>>>(dst, bcnt, W, whi, e, ebl);
    k_main<<<ebl + gemmbl, 512, 0, stream>>>(src, dst, bcnt, gcur, bbase, coarse, x, whi, hs, e, n, ebl);
    k_bfin<<<nb, 512, 0, stream>>>(coarse, bbase, dinv, row_start, ebuf, n, e);
    {
        int blocks = (n + 3) / 4;
        if (blocks > 2048) blocks = 2048;
        k_gather<<<blocks, 256, 0, stream>>>(hs, ebuf, row_start, dinv, b, out, n);
    }
}